// Round 12
// baseline (4426.599 us; speedup 1.0000x reference)
//
#include <hip/hip_runtime.h>

#define HD 256
#define ID 32
#define OD 10
#define SEQ 512
#define SMEM_BYTES 151552   // 16K h dbuf + 4K bias + 128K LDS weight frags

typedef __attribute__((ext_vector_type(4))) float f32x4;
typedef __attribute__((ext_vector_type(8))) unsigned short u16x8;
typedef __attribute__((ext_vector_type(8))) __bf16 bf16x8;

static __device__ __forceinline__ unsigned short f2bf(float f) {
  unsigned u = __builtin_bit_cast(unsigned, f);
  u += 0x7fffu + ((u >> 16) & 1u);          // RNE
  return (unsigned short)(u >> 16);
}
static __device__ __forceinline__ float bf2f(unsigned short s) {
  unsigned u = ((unsigned)s) << 16;
  return __builtin_bit_cast(float, u);
}
static __device__ __forceinline__ f32x4 mfma16(u16x8 a, u16x8 b, f32x4 c) {
  return __builtin_amdgcn_mfma_f32_16x16x32_bf16(
      __builtin_bit_cast(bf16x8, a), __builtin_bit_cast(bf16x8, b), c, 0, 0, 0);
}
// "a"-constraint MFMA (R3-proven bit-exact) + s_nop guard: protects against
// compiler-scheduled VALU writes (e.g. AGPR-spill accvgpr traffic) landing
// within the 2-cycle VALU->MFMA hazard window that the compiler does not
// pad around opaque asm.
static __device__ __forceinline__ void mfma_a(f32x4& d, u16x8 a, const u16x8& b) {
  asm("s_nop 1\n\tv_mfma_f32_16x16x32_bf16 %0, %1, %2, %0"
      : "+v"(d) : "v"(a), "a"(b));
}
static __device__ __forceinline__ float fast_sigmoid(float x) {
  return 1.f / (1.f + __expf(-x));
}
static __device__ __forceinline__ float fast_tanh(float x) {
  return 1.f - 2.f / (__expf(2.f * x) + 1.f);
}

// ---------------------------------------------------------------------------
// Pack [Wx;Wh] (K=288 x N=1024 bf16) fragment-major (round-9 layout, proven).
// frag f = w*144 + (cl*4+g)*9 + kt  (w=wave 0..3 owns units [64w,64w+64))
// lane l slot i -> W[k = 32kt + 8*(l>>4)+i][unit U = 64w + 16cl + (l&15)] gate g
// ---------------------------------------------------------------------------
__global__ void pack_w(const float* __restrict__ Wgx, const float* __restrict__ Wgh,
                       const float* __restrict__ Wix, const float* __restrict__ Wih,
                       const float* __restrict__ Wfx, const float* __restrict__ Wfh,
                       const float* __restrict__ Wox, const float* __restrict__ Woh,
                       unsigned short* __restrict__ Wpk) {
  int p = blockIdx.x * blockDim.x + threadIdx.x;
  if (p >= 576 * 64) return;
  int f = p >> 6, l = p & 63;
  int w = f / 144, r = f % 144;
  int cg = r / 9, kt = r % 9;
  int U = w * 64 + (cg >> 2) * 16 + (l & 15);
  int g = cg & 3;
  const float* Wx[4] = {Wgx, Wix, Wfx, Wox};
  const float* Wh[4] = {Wgh, Wih, Wfh, Woh};
  u16x8 v;
  #pragma unroll
  for (int i = 0; i < 8; ++i) {
    int k = kt * 32 + 8 * (l >> 4) + i;
    float val = (k < ID) ? Wx[g][k * HD + U] : Wh[g][(k - ID) * HD + U];
    v[i] = f2bf(val);
  }
  *(u16x8*)(Wpk + ((size_t)f << 9) + (l << 3)) = v;
}

static __device__ __forceinline__ u16x8 ldfrag(const unsigned short* base, int f) {
  return *(const u16x8*)(base + ((size_t)f << 9));
}

// chain: kt0(stream) -> kt1-3(AGPR asm) -> kt4(stream) -> kt5(VGPR) ->
// kt6(stream) -> kt7,8(LDS). Starts/ends on builtins (hazards compiler-visible).
#define GCHAIN(ACC, G, P2, SN) \
  ACC = mfma16(ax, SN[G], ACC); \
  mfma_a(ACC, ah[0], wa[3*(P2)+0]); \
  mfma_a(ACC, ah[1], wa[3*(P2)+1]); \
  mfma_a(ACC, ah[2], wa[3*(P2)+2]); \
  ACC = mfma16(ah[3], SN[4+(G)], ACC); \
  ACC = mfma16(ah[4], wf5[P2], ACC); \
  ACC = mfma16(ah[5], SN[8+(G)], ACC); \
  ACC = mfma16(ah[6], *(const u16x8*)(wlw + ((size_t)(2*(P2)) << 9)), ACC); \
  ACC = mfma16(ah[7], *(const u16x8*)(wlw + ((size_t)(2*(P2)+1) << 9)), ACC);

// phase PN streamed frags: kt0 (g0..3), kt4 (g0..3), kt6 (g0..3)
#define PREF(PN, SN) \
  SN[0]  = ldfrag(wbase, ((PN)*4+0)*9+0); \
  SN[1]  = ldfrag(wbase, ((PN)*4+1)*9+0); \
  SN[2]  = ldfrag(wbase, ((PN)*4+2)*9+0); \
  SN[3]  = ldfrag(wbase, ((PN)*4+3)*9+0); \
  SN[4]  = ldfrag(wbase, ((PN)*4+0)*9+4); \
  SN[5]  = ldfrag(wbase, ((PN)*4+1)*9+4); \
  SN[6]  = ldfrag(wbase, ((PN)*4+2)*9+4); \
  SN[7]  = ldfrag(wbase, ((PN)*4+3)*9+4); \
  SN[8]  = ldfrag(wbase, ((PN)*4+0)*9+6); \
  SN[9]  = ldfrag(wbase, ((PN)*4+1)*9+6); \
  SN[10] = ldfrag(wbase, ((PN)*4+2)*9+6); \
  SN[11] = ldfrag(wbase, ((PN)*4+3)*9+6);

#define INITACC(CL) \
  { const int ub_ = ubase + 16*(CL); \
    float b0_ = blds[ub_], b1_ = blds[256+ub_]; \
    float b2_ = blds[512+ub_], b3_ = blds[768+ub_]; \
    acc0 = f32x4{b0_,b0_,b0_,b0_}; acc1 = f32x4{b1_,b1_,b1_,b1_}; \
    acc2 = f32x4{b2_,b2_,b2_,b2_}; acc3 = f32x4{b3_,b3_,b3_,b3_}; }

#define GATES(CL) \
  { const int ub_ = ubase + 16*(CL); const int cu_ = ub_ >> 3; \
    _Pragma("unroll") \
    for (int i = 0; i < 4; ++i) { \
      float gg = fast_tanh(acc0[i]); \
      float ii = fast_sigmoid(acc1[i]); \
      float ff = fast_sigmoid(acc2[i]); \
      float oo = fast_sigmoid(acc3[i]); \
      float cc = gg*ii + cst[(CL)*4+i]*ff; \
      cst[(CL)*4+i] = cc; \
      float hh = fast_tanh(cc)*oo; \
      int r2 = 4*l4 + i; \
      ho[r2*256 + ((cu_ ^ r2) << 3) + (ub_ & 7)] = f2bf(hh); \
    } }

// ---------------------------------------------------------------------------
// 16 independent WGs, 256 threads, 1 wave/SIMD (512 unified regs/wave).
// Per wave: 48 frags AGPR (192 AGPR, 64 spare) + 16 VGPR + 32 LDS +
// 48 streamed (kt0,4,6; one-phase-ahead double buffer).
// ---------------------------------------------------------------------------
__global__ void __launch_bounds__(256, 1) lstm_rec(
    const float* __restrict__ x, const unsigned short* __restrict__ Wpk,
    const float* __restrict__ bgp, const float* __restrict__ bip,
    const float* __restrict__ bfp, const float* __restrict__ bop,
    const float* __restrict__ Wph, const float* __restrict__ bpp,
    float* __restrict__ out) {
  extern __shared__ __align__(16) char smem[];
  unsigned short* hbuf = (unsigned short*)smem;            // [2][16][256] bf16
  float* blds = (float*)(smem + 16384);                    // [4][256] bias
  unsigned short* wlds = (unsigned short*)(smem + 20480);  // [4][32][512]

  const int tid = threadIdx.x;
  const int w = tid >> 6, l = tid & 63;
  const int l15 = l & 15, l4 = l >> 4;
  const int b0 = blockIdx.x * 16;

  const unsigned short* wbase = Wpk + (((size_t)w * 144) << 9) + (l << 3);
  unsigned short* wlw = wlds + w * (32 * 512) + (l << 3);

  // ---- stage LDS frags (kt7,8 per (cl,g) pair p) ----
  #pragma unroll
  for (int p = 0; p < 16; ++p) {
    *(u16x8*)(wlw + ((size_t)(2*p) << 9))   = ldfrag(wbase, p*9 + 7);
    *(u16x8*)(wlw + ((size_t)(2*p+1) << 9)) = ldfrag(wbase, p*9 + 8);
  }
  blds[tid]       = bgp[tid];
  blds[256 + tid] = bip[tid];
  blds[512 + tid] = bfp[tid];
  blds[768 + tid] = bop[tid];
  for (int idx = tid; idx < 4096; idx += 256) hbuf[idx] = 0;

  // ---- VGPR-resident frags (kt5) ----
  u16x8 wf5[16];
  #pragma unroll
  for (int p = 0; p < 16; ++p) wf5[p] = ldfrag(wbase, p*9 + 5);

  // ---- AGPR-resident frags: kt1..3 for all 16 pairs (192 AGPRs) ----
  u16x8 wa[48];
  #pragma unroll
  for (int p = 0; p < 16; ++p)
    #pragma unroll
    for (int kt = 1; kt <= 3; ++kt)
      wa[p*3 + kt - 1] = ldfrag(wbase, p*9 + kt);

  float cst[16];
  #pragma unroll
  for (int i = 0; i < 16; ++i) cst[i] = 0.f;

  u16x8 sA[12], sB[12];
  PREF(0, sA)   // phase 0 stream frags

  const int ubase = 64 * w + l15;
  const float* xrow = x + ((size_t)(b0 + l15) * SEQ) * ID + 8 * l4;
  float4 xv0 = *(const float4*)xrow;
  float4 xv1 = *(const float4*)(xrow + 4);

  __syncthreads();

  #pragma unroll 1
  for (int t = 0; t < SEQ; ++t) {
    u16x8 ax;
    ax[0] = f2bf(xv0.x); ax[1] = f2bf(xv0.y); ax[2] = f2bf(xv0.z); ax[3] = f2bf(xv0.w);
    ax[4] = f2bf(xv1.x); ax[5] = f2bf(xv1.y); ax[6] = f2bf(xv1.z); ax[7] = f2bf(xv1.w);
    {
      int tn = (t + 1 < SEQ) ? (t + 1) : t;
      xv0 = *(const float4*)(xrow + (size_t)tn * ID);
      xv1 = *(const float4*)(xrow + (size_t)tn * ID + 4);
    }
    const unsigned short* hb = hbuf + (t & 1) * 4096 + l15 * 256;
    u16x8 ah[8];
    #pragma unroll
    for (int kt = 1; kt <= 8; ++kt) {
      int c32 = 4 * (kt - 1) + l4;
      ah[kt - 1] = *(const u16x8*)(hb + ((c32 ^ l15) << 3));
    }
    unsigned short* ho = hbuf + ((t & 1) ^ 1) * 4096;
    f32x4 acc0, acc1, acc2, acc3;

    // ---- phase 0 ----
    PREF(1, sB)
    INITACC(0)
    GCHAIN(acc0, 0, 0, sA)
    GCHAIN(acc1, 1, 1, sA)
    GCHAIN(acc2, 2, 2, sA)
    GCHAIN(acc3, 3, 3, sA)
    GATES(0)
    // ---- phase 1 ----
    PREF(2, sA)
    INITACC(1)
    GCHAIN(acc0, 0, 4, sB)
    GCHAIN(acc1, 1, 5, sB)
    GCHAIN(acc2, 2, 6, sB)
    GCHAIN(acc3, 3, 7, sB)
    GATES(1)
    // ---- phase 2 ----
    PREF(3, sB)
    INITACC(2)
    GCHAIN(acc0, 0, 8,  sA)
    GCHAIN(acc1, 1, 9,  sA)
    GCHAIN(acc2, 2, 10, sA)
    GCHAIN(acc3, 3, 11, sA)
    GATES(2)
    // ---- phase 3 ----
    PREF(0, sA)
    INITACC(3)
    GCHAIN(acc0, 0, 12, sB)
    GCHAIN(acc1, 1, 13, sB)
    GCHAIN(acc2, 2, 14, sB)
    GCHAIN(acc3, 3, 15, sB)
    GATES(3)

    __syncthreads();   // h_t parity buffer complete
  }

  // ---- epilogue: final h in parity 0; logits + softmax ----
  float* lbuf = (float*)(smem + 16384);   // bias region dead
  __syncthreads();
  if (tid < 16 * OD) {
    int eb = tid & 15, ej = tid >> 4;
    float s = bpp[ej];
    for (int k = 0; k < HD; ++k) {
      int ck = (k >> 3) ^ eb;
      s += bf2f(hbuf[eb * 256 + (ck << 3) + (k & 7)]) * Wph[k * OD + ej];
    }
    lbuf[eb * OD + ej] = s;
  }
  __syncthreads();
  if (tid < 16) {
    float m = -1e30f;
    #pragma unroll
    for (int j = 0; j < OD; ++j) m = fmaxf(m, lbuf[tid * OD + j]);
    float e[OD], sum = 0.f;
    #pragma unroll
    for (int j = 0; j < OD; ++j) { e[j] = __expf(lbuf[tid * OD + j] - m); sum += e[j]; }
    float inv = 1.f / sum;
    #pragma unroll
    for (int j = 0; j < OD; ++j) out[(b0 + tid) * OD + j] = e[j] * inv;
  }
}

extern "C" void kernel_launch(void* const* d_in, const int* in_sizes, int n_in,
                              void* d_out, int out_size, void* d_ws, size_t ws_size,
                              hipStream_t stream) {
  const float* X   = (const float*)d_in[0];
  const float* Wgx = (const float*)d_in[1];
  const float* Wgh = (const float*)d_in[2];
  const float* bg  = (const float*)d_in[3];
  const float* Wix = (const float*)d_in[4];
  const float* Wih = (const float*)d_in[5];
  const float* bi  = (const float*)d_in[6];
  const float* Wfx = (const float*)d_in[7];
  const float* Wfh = (const float*)d_in[8];
  const float* bf  = (const float*)d_in[9];
  const float* Wox = (const float*)d_in[10];
  const float* Woh = (const float*)d_in[11];
  const float* bo  = (const float*)d_in[12];
  const float* Wph = (const float*)d_in[13];
  const float* bp  = (const float*)d_in[14];

  unsigned short* Wpk = (unsigned short*)d_ws;   // 576 KB packed weights

  (void)hipFuncSetAttribute((const void*)lstm_rec,
                            hipFuncAttributeMaxDynamicSharedMemorySize,
                            SMEM_BYTES);

  pack_w<<<dim3(72), dim3(512), 0, stream>>>(Wgx, Wgh, Wix, Wih, Wfx, Wfh,
                                             Wox, Woh, Wpk);
  lstm_rec<<<dim3(16), dim3(256), SMEM_BYTES, stream>>>(
      X, Wpk, bg, bi, bf, bo, Wph, bp, (float*)d_out);
}

// Round 13
// 3457.743 us; speedup vs baseline: 1.2802x; 1.2802x over previous
//
#include <hip/hip_runtime.h>

#define HD 256
#define ID 32
#define OD 10
#define SEQ 512
#define SMEM_BYTES 151552   // 16K h dbuf + 4K bias + 128K LDS weight frags

typedef __attribute__((ext_vector_type(4))) float f32x4;
typedef __attribute__((ext_vector_type(8))) unsigned short u16x8;
typedef __attribute__((ext_vector_type(8))) __bf16 bf16x8;

static __device__ __forceinline__ unsigned short f2bf(float f) {
  unsigned u = __builtin_bit_cast(unsigned, f);
  u += 0x7fffu + ((u >> 16) & 1u);          // RNE
  return (unsigned short)(u >> 16);
}
static __device__ __forceinline__ float bf2f(unsigned short s) {
  unsigned u = ((unsigned)s) << 16;
  return __builtin_bit_cast(float, u);
}
static __device__ __forceinline__ f32x4 mfma16(u16x8 a, u16x8 b, f32x4 c) {
  return __builtin_amdgcn_mfma_f32_16x16x32_bf16(
      __builtin_bit_cast(bf16x8, a), __builtin_bit_cast(bf16x8, b), c, 0, 0, 0);
}
static __device__ __forceinline__ float fast_sigmoid(float x) {
  return 1.f / (1.f + __expf(-x));
}
static __device__ __forceinline__ float fast_tanh(float x) {
  return 1.f - 2.f / (__expf(2.f * x) + 1.f);
}

// ---------------------------------------------------------------------------
// Pack [Wx;Wh] (K=288 x N=1024 bf16) fragment-major (R2 mapping, verified).
// frag f = w*72 + cs*9 + kt  (w = wave 0..7, cs = gate*2 + u, kt = 0..8)
// lane l slot i -> B[k = 32kt + 8*(l>>4) + i][gatecol g*256 + 32w + 16u + (l&15)]
// ---------------------------------------------------------------------------
__global__ void pack_w(const float* __restrict__ Wgx, const float* __restrict__ Wgh,
                       const float* __restrict__ Wix, const float* __restrict__ Wih,
                       const float* __restrict__ Wfx, const float* __restrict__ Wfh,
                       const float* __restrict__ Wox, const float* __restrict__ Woh,
                       unsigned short* __restrict__ Wpk) {
  int p = blockIdx.x * blockDim.x + threadIdx.x;
  if (p >= 576 * 64) return;
  int f = p >> 6, l = p & 63;
  int w = f / 72, rem = f % 72;
  int cs = rem / 9, kt = rem % 9;
  int g = cs >> 1, u = cs & 1;
  int j = 32 * w + 16 * u + (l & 15);
  const float* Wx[4] = {Wgx, Wix, Wfx, Wox};
  const float* Wh[4] = {Wgh, Wih, Wfh, Woh};
  u16x8 v;
  #pragma unroll
  for (int i = 0; i < 8; ++i) {
    int k = kt * 32 + 8 * (l >> 4) + i;
    float val = (k < ID) ? Wx[g][k * HD + j] : Wh[g][(k - ID) * HD + j];
    v[i] = f2bf(val);
  }
  *(u16x8*)(Wpk + ((size_t)f << 9) + (l << 3)) = v;
}

static __device__ __forceinline__ u16x8 ldfrag(const unsigned short* base, int f) {
  return *(const u16x8*)(base + ((size_t)f << 9));
}

// chain for (G,U), cs = 2G+U: resident first, streamed last (latency cover).
// kt1-3 regs, kt7-8 LDS, kt0/4/5/6 streamed (kt4 reg for cs<4).
#define GCHAIN(ACC, G, U, KT4B) \
  ACC = mfma16(ah[0], wr3[(2*(G)+(U))*3+0], ACC); \
  ACC = mfma16(ah[1], wr3[(2*(G)+(U))*3+1], ACC); \
  ACC = mfma16(ah[2], wr3[(2*(G)+(U))*3+2], ACC); \
  ACC = mfma16(ah[6], *(const u16x8*)(wlw + ((size_t)((2*(G)+(U))*2+0) << 9)), ACC); \
  ACC = mfma16(ah[7], *(const u16x8*)(wlw + ((size_t)((2*(G)+(U))*2+1) << 9)), ACC); \
  ACC = mfma16(ax,    S[G], ACC); \
  ACC = mfma16(ah[3], KT4B, ACC); \
  ACC = mfma16(ah[4], S[4+(G)], ACC); \
  ACC = mfma16(ah[5], S[8+(G)], ACC);

// phase-U streamed frags: kt0 (4 gates), kt5, kt6, kt4 for cs=4+U,6+U
#define PREF(U, S) \
  S[0]  = ldfrag(wbase, (0+(U))*9 + 0); \
  S[1]  = ldfrag(wbase, (2+(U))*9 + 0); \
  S[2]  = ldfrag(wbase, (4+(U))*9 + 0); \
  S[3]  = ldfrag(wbase, (6+(U))*9 + 0); \
  S[4]  = ldfrag(wbase, (0+(U))*9 + 5); \
  S[5]  = ldfrag(wbase, (2+(U))*9 + 5); \
  S[6]  = ldfrag(wbase, (4+(U))*9 + 5); \
  S[7]  = ldfrag(wbase, (6+(U))*9 + 5); \
  S[8]  = ldfrag(wbase, (0+(U))*9 + 6); \
  S[9]  = ldfrag(wbase, (2+(U))*9 + 6); \
  S[10] = ldfrag(wbase, (4+(U))*9 + 6); \
  S[11] = ldfrag(wbase, (6+(U))*9 + 6); \
  S[12] = ldfrag(wbase, (4+(U))*9 + 4); \
  S[13] = ldfrag(wbase, (6+(U))*9 + 4);

#define INITACC(U) \
  { const int ub_ = 32*w + 16*(U) + l15; \
    float b0_ = blds[ub_], b1_ = blds[256+ub_]; \
    float b2_ = blds[512+ub_], b3_ = blds[768+ub_]; \
    acc0 = f32x4{b0_,b0_,b0_,b0_}; acc1 = f32x4{b1_,b1_,b1_,b1_}; \
    acc2 = f32x4{b2_,b2_,b2_,b2_}; acc3 = f32x4{b3_,b3_,b3_,b3_}; }

#define GATES(U) \
  { const int ub_ = 32*w + 16*(U) + l15; const int cu_ = ub_ >> 3; \
    _Pragma("unroll") \
    for (int i = 0; i < 4; ++i) { \
      float gg = fast_tanh(acc0[i]); \
      float ii = fast_sigmoid(acc1[i]); \
      float ff = fast_sigmoid(acc2[i]); \
      float oo = fast_sigmoid(acc3[i]); \
      float cc = gg*ii + cst[(U)*4+i]*ff; \
      cst[(U)*4+i] = cc; \
      float hh = fast_tanh(cc)*oo; \
      int r2 = 4*l4 + i; \
      ho[r2*256 + ((cu_ ^ r2) << 3) + (ub_ & 7)] = f2bf(hh); \
    } }

// ---------------------------------------------------------------------------
// 16 independent WGs (one per 16-row batch group), 512 threads = 8 waves,
// 2 waves/SIMD (256 unified regs/wave — R5-proven budget). Wave w owns
// hidden units [32w, 32w+32) across all 4 gates: 72 frags = 28 regs +
// 16 LDS + 28 streamed/step. h in XOR-swizzled LDS double-buffer.
// ---------------------------------------------------------------------------
__global__ void __launch_bounds__(512, 2) lstm_rec(
    const float* __restrict__ x, const unsigned short* __restrict__ Wpk,
    const float* __restrict__ bgp, const float* __restrict__ bip,
    const float* __restrict__ bfp, const float* __restrict__ bop,
    const float* __restrict__ Wph, const float* __restrict__ bpp,
    float* __restrict__ out) {
  extern __shared__ __align__(16) char smem[];
  unsigned short* hbuf = (unsigned short*)smem;            // [2][16][256] bf16
  float* blds = (float*)(smem + 16384);                    // [4][256] bias
  unsigned short* wlds = (unsigned short*)(smem + 20480);  // [8][16][512]

  const int tid = threadIdx.x;
  const int w = tid >> 6, l = tid & 63;
  const int l15 = l & 15, l4 = l >> 4;
  const int b0 = blockIdx.x * 16;

  const unsigned short* wbase = Wpk + (((size_t)w * 72) << 9) + (l << 3);
  unsigned short* wlw = wlds + w * (16 * 512) + (l << 3);

  // ---- stage LDS frags (kt7,8 per cs) ----
  #pragma unroll
  for (int cs = 0; cs < 8; ++cs) {
    *(u16x8*)(wlw + ((size_t)(2*cs)   << 9)) = ldfrag(wbase, cs*9 + 7);
    *(u16x8*)(wlw + ((size_t)(2*cs+1) << 9)) = ldfrag(wbase, cs*9 + 8);
  }
  // bias to LDS; zero h parity 0
  if (tid < 256) {
    blds[tid]       = bgp[tid];
    blds[256 + tid] = bip[tid];
    blds[512 + tid] = bfp[tid];
    blds[768 + tid] = bop[tid];
  }
  for (int idx = tid; idx < 4096; idx += 512) hbuf[idx] = 0;

  // ---- register-resident frags: kt1-3 all cs (24) + kt4 cs0-3 (4) ----
  u16x8 wr3[24], wr4[4];
  #pragma unroll
  for (int cs = 0; cs < 8; ++cs)
    #pragma unroll
    for (int kt = 1; kt <= 3; ++kt)
      wr3[cs*3 + kt - 1] = ldfrag(wbase, cs*9 + kt);
  #pragma unroll
  for (int cs = 0; cs < 4; ++cs) wr4[cs] = ldfrag(wbase, cs*9 + 4);

  float cst[8];
  #pragma unroll
  for (int i = 0; i < 8; ++i) cst[i] = 0.f;

  const float* xrow = x + ((size_t)(b0 + l15) * SEQ) * ID + 8 * l4;
  float4 xv0 = *(const float4*)xrow;
  float4 xv1 = *(const float4*)(xrow + 4);

  __syncthreads();

  #pragma unroll 1
  for (int t = 0; t < SEQ; ++t) {
    u16x8 ax;
    ax[0] = f2bf(xv0.x); ax[1] = f2bf(xv0.y); ax[2] = f2bf(xv0.z); ax[3] = f2bf(xv0.w);
    ax[4] = f2bf(xv1.x); ax[5] = f2bf(xv1.y); ax[6] = f2bf(xv1.z); ax[7] = f2bf(xv1.w);
    {
      int tn = (t + 1 < SEQ) ? (t + 1) : t;
      xv0 = *(const float4*)(xrow + (size_t)tn * ID);
      xv1 = *(const float4*)(xrow + (size_t)tn * ID + 4);
    }
    const unsigned short* hb = hbuf + (t & 1) * 4096 + l15 * 256;
    u16x8 ah[8];
    #pragma unroll
    for (int kt = 1; kt <= 8; ++kt) {
      int c32 = 4 * (kt - 1) + l4;
      ah[kt - 1] = *(const u16x8*)(hb + ((c32 ^ l15) << 3));
    }
    unsigned short* ho = hbuf + ((t & 1) ^ 1) * 4096;
    f32x4 acc0, acc1, acc2, acc3;
    u16x8 S[14];

    // ---- phase 0 (units 32w..32w+15) ----
    PREF(0, S)
    INITACC(0)
    GCHAIN(acc0, 0, 0, wr4[0])
    GCHAIN(acc1, 1, 0, wr4[2])
    GCHAIN(acc2, 2, 0, S[12])
    GCHAIN(acc3, 3, 0, S[13])
    GATES(0)
    // ---- phase 1 (units 32w+16..32w+31) ----
    PREF(1, S)
    INITACC(1)
    GCHAIN(acc0, 0, 1, wr4[1])
    GCHAIN(acc1, 1, 1, wr4[3])
    GCHAIN(acc2, 2, 1, S[12])
    GCHAIN(acc3, 3, 1, S[13])
    GATES(1)

    __syncthreads();   // h_t parity buffer complete
  }

  // ---- epilogue: final h in parity 0; logits + softmax ----
  float* lbuf = (float*)(smem + 16384);   // bias region dead
  if (tid < 16 * OD) {
    int eb = tid & 15, ej = tid >> 4;
    float s = bpp[ej];
    for (int k = 0; k < HD; ++k) {
      int ck = (k >> 3) ^ eb;
      s += bf2f(hbuf[eb * 256 + (ck << 3) + (k & 7)]) * Wph[k * OD + ej];
    }
    lbuf[eb * OD + ej] = s;
  }
  __syncthreads();
  if (tid < 16) {
    float m = -1e30f;
    #pragma unroll
    for (int j = 0; j < OD; ++j) m = fmaxf(m, lbuf[tid * OD + j]);
    float e[OD], sum = 0.f;
    #pragma unroll
    for (int j = 0; j < OD; ++j) { e[j] = __expf(lbuf[tid * OD + j] - m); sum += e[j]; }
    float inv = 1.f / sum;
    #pragma unroll
    for (int j = 0; j < OD; ++j) out[(b0 + tid) * OD + j] = e[j] * inv;
  }
}

extern "C" void kernel_launch(void* const* d_in, const int* in_sizes, int n_in,
                              void* d_out, int out_size, void* d_ws, size_t ws_size,
                              hipStream_t stream) {
  const float* X   = (const float*)d_in[0];
  const float* Wgx = (const float*)d_in[1];
  const float* Wgh = (const float*)d_in[2];
  const float* bg  = (const float*)d_in[3];
  const float* Wix = (const float*)d_in[4];
  const float* Wih = (const float*)d_in[5];
  const float* bi  = (const float*)d_in[6];
  const float* Wfx = (const float*)d_in[7];
  const float* Wfh = (const float*)d_in[8];
  const float* bf  = (const float*)d_in[9];
  const float* Wox = (const float*)d_in[10];
  const float* Woh = (const float*)d_in[11];
  const float* bo  = (const float*)d_in[12];
  const float* Wph = (const float*)d_in[13];
  const float* bp  = (const float*)d_in[14];

  unsigned short* Wpk = (unsigned short*)d_ws;   // 576 KB packed weights

  (void)hipFuncSetAttribute((const void*)lstm_rec,
                            hipFuncAttributeMaxDynamicSharedMemorySize,
                            SMEM_BYTES);

  pack_w<<<dim3(72), dim3(512), 0, stream>>>(Wgx, Wgh, Wix, Wih, Wfx, Wfh,
                                             Wox, Woh, Wpk);
  lstm_rec<<<dim3(16), dim3(512), SMEM_BYTES, stream>>>(
      X, Wpk, bg, bi, bf, bo, Wph, bp, (float*)d_out);
}

// Round 14
// 2259.127 us; speedup vs baseline: 1.9594x; 1.5306x over previous
//
#include <hip/hip_runtime.h>

#define HD 256
#define ID 32
#define OD 10
#define SEQ 512
#define SMEM_BYTES 151552   // 16K h dbuf + 4K bias + 128K LDS weight frags

typedef __attribute__((ext_vector_type(4))) float f32x4;
typedef __attribute__((ext_vector_type(4))) unsigned int u32x4;
typedef __attribute__((ext_vector_type(8))) unsigned short u16x8;
typedef __attribute__((ext_vector_type(8))) __bf16 bf16x8;

static __device__ __forceinline__ unsigned short f2bf(float f) {
  unsigned u = __builtin_bit_cast(unsigned, f);
  u += 0x7fffu + ((u >> 16) & 1u);          // RNE
  return (unsigned short)(u >> 16);
}
static __device__ __forceinline__ float bf2f(unsigned short s) {
  unsigned u = ((unsigned)s) << 16;
  return __builtin_bit_cast(float, u);
}
// packed f32->bf16 (RNE, matches f2bf): dst.lo16 = cvt(a), dst.hi16 = cvt(b)
static __device__ __forceinline__ unsigned cvtpk(float a, float b) {
  unsigned r;
  asm("v_cvt_pk_bf16_f32 %0, %1, %2" : "=v"(r) : "v"(a), "v"(b));
  return r;
}
static __device__ __forceinline__ f32x4 mfma16(u16x8 a, u16x8 b, f32x4 c) {
  return __builtin_amdgcn_mfma_f32_16x16x32_bf16(
      __builtin_bit_cast(bf16x8, a), __builtin_bit_cast(bf16x8, b), c, 0, 0, 0);
}
// v_rcp_f32-based gates: kills IEEE-div expansion (~15 instr -> 1 trans op)
static __device__ __forceinline__ float fast_sigmoid(float x) {
  return __builtin_amdgcn_rcpf(1.f + __expf(-x));
}
static __device__ __forceinline__ float fast_tanh(float x) {
  return 1.f - 2.f * __builtin_amdgcn_rcpf(__expf(2.f * x) + 1.f);
}

// ---------------------------------------------------------------------------
// Pack [Wx;Wh] (K=288 x N=1024 bf16) fragment-major (R2 mapping, verified).
// frag f = w*72 + cs*9 + kt  (w = wave 0..7, cs = gate*2 + u, kt = 0..8)
// lane l slot i -> B[k = 32kt + 8*(l>>4) + i][gatecol g*256 + 32w + 16u + (l&15)]
// ---------------------------------------------------------------------------
__global__ void pack_w(const float* __restrict__ Wgx, const float* __restrict__ Wgh,
                       const float* __restrict__ Wix, const float* __restrict__ Wih,
                       const float* __restrict__ Wfx, const float* __restrict__ Wfh,
                       const float* __restrict__ Wox, const float* __restrict__ Woh,
                       unsigned short* __restrict__ Wpk) {
  int p = blockIdx.x * blockDim.x + threadIdx.x;
  if (p >= 576 * 64) return;
  int f = p >> 6, l = p & 63;
  int w = f / 72, rem = f % 72;
  int cs = rem / 9, kt = rem % 9;
  int g = cs >> 1, u = cs & 1;
  int j = 32 * w + 16 * u + (l & 15);
  const float* Wx[4] = {Wgx, Wix, Wfx, Wox};
  const float* Wh[4] = {Wgh, Wih, Wfh, Woh};
  u16x8 v;
  #pragma unroll
  for (int i = 0; i < 8; ++i) {
    int k = kt * 32 + 8 * (l >> 4) + i;
    float val = (k < ID) ? Wx[g][k * HD + j] : Wh[g][(k - ID) * HD + j];
    v[i] = f2bf(val);
  }
  *(u16x8*)(Wpk + ((size_t)f << 9) + (l << 3)) = v;
}

static __device__ __forceinline__ u16x8 ldfrag(const unsigned short* base, int f) {
  return *(const u16x8*)(base + ((size_t)f << 9));
}

// resident part of chain (G,U): kt1-3 regs, kt7-8 LDS — issued FIRST
#define GRES(ACC, G, U) \
  ACC = mfma16(ah[0], wr3[(2*(G)+(U))*3+0], ACC); \
  ACC = mfma16(ah[1], wr3[(2*(G)+(U))*3+1], ACC); \
  ACC = mfma16(ah[2], wr3[(2*(G)+(U))*3+2], ACC); \
  ACC = mfma16(ah[6], *(const u16x8*)(wlw + ((size_t)((2*(G)+(U))*2+0) << 9)), ACC); \
  ACC = mfma16(ah[7], *(const u16x8*)(wlw + ((size_t)((2*(G)+(U))*2+1) << 9)), ACC);
// streamed part — issued LAST (~500 cy after PREF -> full L2 latency cover)
#define GSTR(ACC, G, KT4B) \
  ACC = mfma16(ax,    S[G], ACC); \
  ACC = mfma16(ah[3], KT4B, ACC); \
  ACC = mfma16(ah[4], S[4+(G)], ACC); \
  ACC = mfma16(ah[5], S[8+(G)], ACC);

// phase-U streamed frags: kt0 (4 gates), kt5, kt6, kt4 for cs=4+U,6+U
#define PREF(U, S) \
  S[0]  = ldfrag(wbase, (0+(U))*9 + 0); \
  S[1]  = ldfrag(wbase, (2+(U))*9 + 0); \
  S[2]  = ldfrag(wbase, (4+(U))*9 + 0); \
  S[3]  = ldfrag(wbase, (6+(U))*9 + 0); \
  S[4]  = ldfrag(wbase, (0+(U))*9 + 5); \
  S[5]  = ldfrag(wbase, (2+(U))*9 + 5); \
  S[6]  = ldfrag(wbase, (4+(U))*9 + 5); \
  S[7]  = ldfrag(wbase, (6+(U))*9 + 5); \
  S[8]  = ldfrag(wbase, (0+(U))*9 + 6); \
  S[9]  = ldfrag(wbase, (2+(U))*9 + 6); \
  S[10] = ldfrag(wbase, (4+(U))*9 + 6); \
  S[11] = ldfrag(wbase, (6+(U))*9 + 6); \
  S[12] = ldfrag(wbase, (4+(U))*9 + 4); \
  S[13] = ldfrag(wbase, (6+(U))*9 + 4);

#define INITACC(U) \
  { const int ub_ = 32*w + 16*(U) + l15; \
    float b0_ = blds[ub_], b1_ = blds[256+ub_]; \
    float b2_ = blds[512+ub_], b3_ = blds[768+ub_]; \
    acc0 = f32x4{b0_,b0_,b0_,b0_}; acc1 = f32x4{b1_,b1_,b1_,b1_}; \
    acc2 = f32x4{b2_,b2_,b2_,b2_}; acc3 = f32x4{b3_,b3_,b3_,b3_}; }

#define GATES(U) \
  { const int ub_ = 32*w + 16*(U) + l15; const int cu_ = ub_ >> 3; \
    _Pragma("unroll") \
    for (int i = 0; i < 4; ++i) { \
      float gg = fast_tanh(acc0[i]); \
      float ii = fast_sigmoid(acc1[i]); \
      float ff = fast_sigmoid(acc2[i]); \
      float oo = fast_sigmoid(acc3[i]); \
      float cc = gg*ii + cst[(U)*4+i]*ff; \
      cst[(U)*4+i] = cc; \
      float hh = fast_tanh(cc)*oo; \
      int r2 = 4*l4 + i; \
      ho[r2*256 + ((cu_ ^ r2) << 3) + (ub_ & 7)] = \
          (unsigned short)cvtpk(hh, hh); \
    } }

// ---------------------------------------------------------------------------
// 16 independent WGs (one per 16-row batch group), 512 threads = 8 waves,
// 2 waves/SIMD (256 unified regs/wave). Wave w owns hidden units
// [32w, 32w+32) across all 4 gates: 72 frags = 28 regs + 16 LDS +
// 28 streamed/step. h in XOR-swizzled LDS double-buffer.
// ---------------------------------------------------------------------------
__global__ void __launch_bounds__(512, 2) lstm_rec(
    const float* __restrict__ x, const unsigned short* __restrict__ Wpk,
    const float* __restrict__ bgp, const float* __restrict__ bip,
    const float* __restrict__ bfp, const float* __restrict__ bop,
    const float* __restrict__ Wph, const float* __restrict__ bpp,
    float* __restrict__ out) {
  extern __shared__ __align__(16) char smem[];
  unsigned short* hbuf = (unsigned short*)smem;            // [2][16][256] bf16
  float* blds = (float*)(smem + 16384);                    // [4][256] bias
  unsigned short* wlds = (unsigned short*)(smem + 20480);  // [8][16][512]

  const int tid = threadIdx.x;
  const int w = tid >> 6, l = tid & 63;
  const int l15 = l & 15, l4 = l >> 4;
  const int b0 = blockIdx.x * 16;

  const unsigned short* wbase = Wpk + (((size_t)w * 72) << 9) + (l << 3);
  unsigned short* wlw = wlds + w * (16 * 512) + (l << 3);

  // ---- stage LDS frags (kt7,8 per cs) ----
  #pragma unroll
  for (int cs = 0; cs < 8; ++cs) {
    *(u16x8*)(wlw + ((size_t)(2*cs)   << 9)) = ldfrag(wbase, cs*9 + 7);
    *(u16x8*)(wlw + ((size_t)(2*cs+1) << 9)) = ldfrag(wbase, cs*9 + 8);
  }
  // bias to LDS; zero h parity 0
  if (tid < 256) {
    blds[tid]       = bgp[tid];
    blds[256 + tid] = bip[tid];
    blds[512 + tid] = bfp[tid];
    blds[768 + tid] = bop[tid];
  }
  for (int idx = tid; idx < 4096; idx += 512) hbuf[idx] = 0;

  // ---- register-resident frags: kt1-3 all cs (24) + kt4 cs0-3 (4) ----
  u16x8 wr3[24], wr4[4];
  #pragma unroll
  for (int cs = 0; cs < 8; ++cs)
    #pragma unroll
    for (int kt = 1; kt <= 3; ++kt)
      wr3[cs*3 + kt - 1] = ldfrag(wbase, cs*9 + kt);
  #pragma unroll
  for (int cs = 0; cs < 4; ++cs) wr4[cs] = ldfrag(wbase, cs*9 + 4);

  float cst[8];
  #pragma unroll
  for (int i = 0; i < 8; ++i) cst[i] = 0.f;

  const float* xrow = x + ((size_t)(b0 + l15) * SEQ) * ID + 8 * l4;
  float4 xv0 = *(const float4*)xrow;
  float4 xv1 = *(const float4*)(xrow + 4);

  __syncthreads();

  #pragma unroll 1
  for (int t = 0; t < SEQ; ++t) {
    u16x8 ax;
    {
      u32x4 axi;
      axi.x = cvtpk(xv0.x, xv0.y);
      axi.y = cvtpk(xv0.z, xv0.w);
      axi.z = cvtpk(xv1.x, xv1.y);
      axi.w = cvtpk(xv1.z, xv1.w);
      ax = __builtin_bit_cast(u16x8, axi);
    }
    {
      int tn = (t + 1 < SEQ) ? (t + 1) : t;
      xv0 = *(const float4*)(xrow + (size_t)tn * ID);
      xv1 = *(const float4*)(xrow + (size_t)tn * ID + 4);
    }
    const unsigned short* hb = hbuf + (t & 1) * 4096 + l15 * 256;
    u16x8 ah[8];
    #pragma unroll
    for (int kt = 1; kt <= 8; ++kt) {
      int c32 = 4 * (kt - 1) + l4;
      ah[kt - 1] = *(const u16x8*)(hb + ((c32 ^ l15) << 3));
    }
    unsigned short* ho = hbuf + ((t & 1) ^ 1) * 4096;
    f32x4 acc0, acc1, acc2, acc3;
    u16x8 S[14];

    // ---- phase 0 (units 32w..32w+15): resident first, streamed last ----
    PREF(0, S)
    INITACC(0)
    GRES(acc0, 0, 0)
    GRES(acc1, 1, 0)
    GRES(acc2, 2, 0)
    GRES(acc3, 3, 0)
    GSTR(acc0, 0, wr4[0])
    GSTR(acc1, 1, wr4[2])
    GSTR(acc2, 2, S[12])
    GSTR(acc3, 3, S[13])
    GATES(0)
    // ---- phase 1 (units 32w+16..32w+31) ----
    PREF(1, S)
    INITACC(1)
    GRES(acc0, 0, 1)
    GRES(acc1, 1, 1)
    GRES(acc2, 2, 1)
    GRES(acc3, 3, 1)
    GSTR(acc0, 0, wr4[1])
    GSTR(acc1, 1, wr4[3])
    GSTR(acc2, 2, S[12])
    GSTR(acc3, 3, S[13])
    GATES(1)

    __syncthreads();   // h_t parity buffer complete
  }

  // ---- epilogue: final h in parity 0; logits + softmax ----
  float* lbuf = (float*)(smem + 16384);   // bias region dead
  if (tid < 16 * OD) {
    int eb = tid & 15, ej = tid >> 4;
    float s = bpp[ej];
    for (int k = 0; k < HD; ++k) {
      int ck = (k >> 3) ^ eb;
      s += bf2f(hbuf[eb * 256 + (ck << 3) + (k & 7)]) * Wph[k * OD + ej];
    }
    lbuf[eb * OD + ej] = s;
  }
  __syncthreads();
  if (tid < 16) {
    float m = -1e30f;
    #pragma unroll
    for (int j = 0; j < OD; ++j) m = fmaxf(m, lbuf[tid * OD + j]);
    float e[OD], sum = 0.f;
    #pragma unroll
    for (int j = 0; j < OD; ++j) { e[j] = __expf(lbuf[tid * OD + j] - m); sum += e[j]; }
    float inv = 1.f / sum;
    #pragma unroll
    for (int j = 0; j < OD; ++j) out[(b0 + tid) * OD + j] = e[j] * inv;
  }
}

extern "C" void kernel_launch(void* const* d_in, const int* in_sizes, int n_in,
                              void* d_out, int out_size, void* d_ws, size_t ws_size,
                              hipStream_t stream) {
  const float* X   = (const float*)d_in[0];
  const float* Wgx = (const float*)d_in[1];
  const float* Wgh = (const float*)d_in[2];
  const float* bg  = (const float*)d_in[3];
  const float* Wix = (const float*)d_in[4];
  const float* Wih = (const float*)d_in[5];
  const float* bi  = (const float*)d_in[6];
  const float* Wfx = (const float*)d_in[7];
  const float* Wfh = (const float*)d_in[8];
  const float* bf  = (const float*)d_in[9];
  const float* Wox = (const float*)d_in[10];
  const float* Woh = (const float*)d_in[11];
  const float* bo  = (const float*)d_in[12];
  const float* Wph = (const float*)d_in[13];
  const float* bp  = (const float*)d_in[14];

  unsigned short* Wpk = (unsigned short*)d_ws;   // 576 KB packed weights

  (void)hipFuncSetAttribute((const void*)lstm_rec,
                            hipFuncAttributeMaxDynamicSharedMemorySize,
                            SMEM_BYTES);

  pack_w<<<dim3(72), dim3(512), 0, stream>>>(Wgx, Wgh, Wix, Wih, Wfx, Wfh,
                                             Wox, Woh, Wpk);
  lstm_rec<<<dim3(16), dim3(512), SMEM_BYTES, stream>>>(
      X, Wpk, bg, bi, bf, bo, Wph, bp, (float*)d_out);
}